// Round 10
// baseline (1037.017 us; speedup 1.0000x reference)
//
#include <hip/hip_runtime.h>

// ---------------- problem constants ----------------
#define NVEC  131072      // 32*4096 vectors
#define DIM   64
#define K     512
#define DECAYF 0.99f
#define OMDF   0.01f
#define EPSF   1e-5f
#define NBLK_ASSIGN (NVEC / 64)   // 2048 blocks, 64 vectors each (R0 layout)

// ---------------- output layout (floats, concatenated in return order) ----
#define Q_OFF    0
#define DIFF_OFF 8388608
#define IND_OFF  8388609
#define NE_OFF   8519681
#define NCS_OFF  8552449
#define NEA_OFF  8552961

// ---------------- ws layout (floats) — ~1.2 MB ----
#define ET_OFF    0        // E^T : K x DIM
#define C_OFF     32768    // np-order sum(E*E, axis=0) : K
#define DPART_OFF 33280    // per-assign-block diff partials : 2048
#define INDI_OFF  35328    // int copy of indices : NVEC
#define PCNT_OFF  166400   // count partials : 4 x K
#define PESUM_OFF 168448   // esum partials : 4 x K x DIM
#define NSH_OFF   299520   // scalar n (1 float) for split finalize
// end: 299521 floats = 1.17 MB (known-safe: r4 used 1.33 MB)

// ============ prep: transpose embed -> E^T, C_j = np.sum(E*E, axis=0) ====
__global__ __launch_bounds__(256) void vq_prep(const float* __restrict__ embed,
                                               float* __restrict__ ws) {
    #pragma clang fp contract(off)
    int j = blockIdx.x * 256 + threadIdx.x;
    float c = 0.0f;
    for (int d = 0; d < DIM; ++d) {
        float v = embed[d * K + j];           // coalesced across j
        ws[ET_OFF + j * DIM + d] = v;
        float t = v * v;
        c = c + t;
    }
    ws[C_OFF + j] = c;
}

// ============ main: np-fp32-replica argmin, VMEM double-buffered e-stream =
// Pipe history (measured): SMEM stream is structurally cornered — prefetch
// depth is SGPR-bound, and the scheduler's workaround (v_mov s->v copies to
// free SGPRs) costs either 2.4x VALU (R1, R=1) or ~32-reg spill (R7/R8/R9,
// R=2, spill persisted across unroll/epilogue changes). LDS broadcast
// oversubscribes the DS pipe 3x (R3). Naive per-lane VMEM exposes latency
// (R2: 1 w/SIMD, no pipeline, vmcnt drained per group).
// THIS ROUND: R0's proven 64-vector/4-wave/j-split kernel with ONE change:
// e arrives via VMEM (opaque lane-zero address -> global_load, broadcast
// line) into an EXPLICIT double-buffered pair of full-row float4[16]
// buffers. Loads for row j+1 issue before computing row j: ~256 cyc of
// compute covers the ~200 cyc L2-hit latency; 2 waves/SIMD add slack.
// Budget: pins 64 + buffers 128 + working ~25 = ~217 < 256 under
// waves_per_eu(2) -> no spill possible, and FMA reads VGPRs directly (no
// mov inflation): busy ~= the 55-60 µs floor.
// Per-(v,j) fp32 sequence bit-identical to R0's passing kernel: d-ascending
// single fmaf chain, t1=2m (exact), t2=A-t1, dist=t2+C[j]; A = exact
// 8-accumulator pairwise; strict '<' ascending j + 4-way merge with
// (d2<bd)||(d2==bd&&i2<bi) = numpy first-min. Loads don't round: only the
// delivery pipe changed.
__global__ __launch_bounds__(256)
__attribute__((amdgpu_waves_per_eu(2)))
void vq_assign(
    const float* __restrict__ x,
    const float* __restrict__ ET,      // ws + ET_OFF
    const float* __restrict__ C,       // ws + C_OFF
    int*   __restrict__ indI,          // ws + INDI_OFF
    float* __restrict__ dpart,         // ws + DPART_OFF
    float* __restrict__ out)
{
    #pragma clang fp contract(off)
    __shared__ float sd[4][64];
    __shared__ int   si[4][64];
    __shared__ int   sbest[64];
    __shared__ float wdl[4];

    int lane = threadIdx.x & 63;
    int wq   = __builtin_amdgcn_readfirstlane(threadIdx.x >> 6); // 0..3
    int v    = blockIdx.x * 64 + lane;
    const float* fx = x + (size_t)v * DIM;

    float f[DIM];
    #pragma unroll
    for (int k = 0; k < DIM / 4; ++k) {
        float4 t = ((const float4*)fx)[k];
        f[4*k+0] = t.x; f[4*k+1] = t.y; f[4*k+2] = t.z; f[4*k+3] = t.w;
    }

    // Pin f[0..63] in VGPRs (identity asm: values defined by asm can't be
    // rematerialized from memory). Pins die at the end of the j-loop; the
    // epilogue reloads x quarters (R0's proven pattern).
    #define PIN16(b) asm volatile("" \
        : "+v"(f[(b)+0]),  "+v"(f[(b)+1]),  "+v"(f[(b)+2]),  "+v"(f[(b)+3]), \
          "+v"(f[(b)+4]),  "+v"(f[(b)+5]),  "+v"(f[(b)+6]),  "+v"(f[(b)+7]), \
          "+v"(f[(b)+8]),  "+v"(f[(b)+9]),  "+v"(f[(b)+10]), "+v"(f[(b)+11]), \
          "+v"(f[(b)+12]), "+v"(f[(b)+13]), "+v"(f[(b)+14]), "+v"(f[(b)+15]))
    PIN16(0); PIN16(16); PIN16(32); PIN16(48);
    #undef PIN16

    // A = np.sum(f*f, axis=1): numpy pairwise, n=64 -> 8 accumulators over
    // strides of 8, then ((r0+r1)+(r2+r3))+((r4+r5)+(r6+r7)). Plain mul+add.
    float r[8];
    #pragma unroll
    for (int k = 0; k < 8; ++k) r[k] = f[k] * f[k];
    #pragma unroll
    for (int b = 1; b < 8; ++b) {
        #pragma unroll
        for (int k = 0; k < 8; ++k) {
            float t = f[8*b + k] * f[8*b + k];
            r[k] = r[k] + t;
        }
    }
    float A = ((r[0] + r[1]) + (r[2] + r[3])) + ((r[4] + r[5]) + (r[6] + r[7]));

    // Opaque lane-zero: forces e-loads onto the VMEM path (VGPR address ->
    // global_load; uniform across lanes -> one broadcast line per load).
    int zoff = 0;
    asm volatile("" : "+v"(zoff));
    const float* ebase = ET + (size_t)wq * 128 * DIM + zoff;
    const float* Cseg  = C + wq * 128;          // tiny: stays scalar

    // Double-buffered full-row staging: bA holds row jj, bB row jj+1.
    float4 bA[16], bB[16];
    #pragma unroll
    for (int k = 0; k < 16; ++k) bA[k] = ((const float4*)ebase)[k];  // row 0

    float bestd = 3.0e38f;
    int   besti = wq * 128;
    #pragma unroll 1
    for (int jj = 0; jj < 128; jj += 2) {
        // prefetch row jj+1 while computing row jj
        {
            const float4* src = (const float4*)(ebase + (size_t)(jj + 1) * DIM);
            #pragma unroll
            for (int k = 0; k < 16; ++k) bB[k] = src[k];
        }
        {   // compute row jj from bA — d-ascending single chain (R0 exact)
            float m = 0.0f;
            #pragma unroll
            for (int k = 0; k < 16; ++k) {
                float4 ev = bA[k];
                m = __builtin_fmaf(f[4*k+0], ev.x, m);
                m = __builtin_fmaf(f[4*k+1], ev.y, m);
                m = __builtin_fmaf(f[4*k+2], ev.z, m);
                m = __builtin_fmaf(f[4*k+3], ev.w, m);
            }
            float t1 = 2.0f * m;             // exact (x2)
            float t2 = A - t1;               // rounded
            float dist = t2 + Cseg[jj];      // rounded
            if (dist < bestd) { bestd = dist; besti = wq * 128 + jj; }
        }
        // prefetch row jj+2 while computing row jj+1
        if (jj + 2 < 128) {
            const float4* src = (const float4*)(ebase + (size_t)(jj + 2) * DIM);
            #pragma unroll
            for (int k = 0; k < 16; ++k) bA[k] = src[k];
        }
        {   // compute row jj+1 from bB
            float m = 0.0f;
            #pragma unroll
            for (int k = 0; k < 16; ++k) {
                float4 ev = bB[k];
                m = __builtin_fmaf(f[4*k+0], ev.x, m);
                m = __builtin_fmaf(f[4*k+1], ev.y, m);
                m = __builtin_fmaf(f[4*k+2], ev.z, m);
                m = __builtin_fmaf(f[4*k+3], ev.w, m);
            }
            float t1 = 2.0f * m;
            float t2 = A - t1;
            float dist = t2 + Cseg[jj + 1];
            if (dist < bestd) { bestd = dist; besti = wq * 128 + jj + 1; }
        }
    }

    sd[wq][lane] = bestd;
    si[wq][lane] = besti;
    __syncthreads();

    if (wq == 0) {
        // 4-way merge, ascending q, tie -> smaller index: numpy first-min.
        float bd = sd[0][lane];
        int   bi = si[0][lane];
        #pragma unroll
        for (int q = 1; q < 4; ++q) {
            float d2 = sd[q][lane];
            int   i2 = si[q][lane];
            if (d2 < bd || (d2 == bd && i2 < bi)) { bd = d2; bi = i2; }
        }
        sbest[lane] = bi;
        out[IND_OFF + v] = (float)bi;    // coalesced
        indI[v] = bi;                    // int copy for vq_stats
    }
    __syncthreads();

    // epilogue (R0 exact): wave w handles a 16-float quarter of each row;
    // x quarter reloaded from global (L1-hot; same bits as pinned copy).
    int bi = sbest[lane];
    const float* qrow = ET + (size_t)bi * DIM + wq * 16;
    const float* xrow = fx + wq * 16;
    float* orow = out + Q_OFF + (size_t)v * DIM + wq * 16;
    float dl = 0.0f;
    #pragma unroll
    for (int k = 0; k < 4; ++k) {
        float4 tq = ((const float4*)qrow)[k];
        float4 tx = ((const float4*)xrow)[k];
        float r0 = tq.x - tx.x;
        float r1 = tq.y - tx.y;
        float r2 = tq.z - tx.z;
        float r3 = tq.w - tx.w;
        dl = __builtin_fmaf(r0, r0, dl); dl = __builtin_fmaf(r1, r1, dl);
        dl = __builtin_fmaf(r2, r2, dl); dl = __builtin_fmaf(r3, r3, dl);
        ((float4*)orow)[k] = tq;
    }

    #pragma unroll
    for (int off = 32; off > 0; off >>= 1) dl += __shfl_down(dl, off);
    if (lane == 0) wdl[wq] = dl;
    __syncthreads();
    if (threadIdx.x == 0)
        dpart[blockIdx.x] = ((wdl[0] + wdl[1]) + (wdl[2] + wdl[3]));
}

// ============ stats: 4 blocks x 8 waves per code, int4 ballot scan =======
__global__ __launch_bounds__(512) void vq_stats(
    const float* __restrict__ x,
    const int* __restrict__ indI,      // ws + INDI_OFF
    float* __restrict__ pcnt,          // ws + PCNT_OFF   [4][K]
    float* __restrict__ pesum)         // ws + PESUM_OFF  [4][K][DIM]
{
    __shared__ float p[8][DIM];
    __shared__ float c[8];
    int j    = blockIdx.x >> 2;
    int q    = blockIdx.x & 3;
    int lane = threadIdx.x & 63;
    int w    = __builtin_amdgcn_readfirstlane(threadIdx.x >> 6);

    int seg  = q * 8 + w;              // 0..31
    int base = seg * (NVEC / 32);      // 4096 ids per segment

    float acc = 0.0f;
    int   cnt = 0;
    for (int i = 0; i < NVEC / 32; i += 256) {
        int4 idv = ((const int4*)(indI + base + i))[lane];  // 256 ids/wave
        unsigned long long m0 = __ballot(idv.x == j);
        unsigned long long m1 = __ballot(idv.y == j);
        unsigned long long m2 = __ballot(idv.z == j);
        unsigned long long m3 = __ballot(idv.w == j);
        cnt += (int)(__popcll(m0) + __popcll(m1) + __popcll(m2) + __popcll(m3));
        while (m0) { int b = __builtin_ctzll(m0); m0 &= m0 - 1;
                     acc += x[(size_t)(base + i + 4*b + 0) * DIM + lane]; }
        while (m1) { int b = __builtin_ctzll(m1); m1 &= m1 - 1;
                     acc += x[(size_t)(base + i + 4*b + 1) * DIM + lane]; }
        while (m2) { int b = __builtin_ctzll(m2); m2 &= m2 - 1;
                     acc += x[(size_t)(base + i + 4*b + 2) * DIM + lane]; }
        while (m3) { int b = __builtin_ctzll(m3); m3 &= m3 - 1;
                     acc += x[(size_t)(base + i + 4*b + 3) * DIM + lane]; }
    }
    p[w][lane] = acc;
    if (lane == 0) c[w] = (float)cnt;
    __syncthreads();
    if (w == 0) {
        float s = ((p[0][lane] + p[1][lane]) + (p[2][lane] + p[3][lane]))
                + ((p[4][lane] + p[5][lane]) + (p[6][lane] + p[7][lane]));
        pesum[((size_t)q * K + j) * DIM + lane] = s;
        if (lane == 0)
            pcnt[q * K + j] = ((c[0] + c[1]) + (c[2] + c[3]))
                            + ((c[4] + c[5]) + (c[6] + c[7]));
    }
}

// ============ finalize stage 1: scalars (ncs, n, diff) — 1 block =========
__global__ __launch_bounds__(512) void vq_finalize1(
    const float* __restrict__ cluster_size,
    float* __restrict__ ws,
    float* __restrict__ out)
{
    __shared__ float wsum[8];
    __shared__ float dsum_sh[8];
    int j = threadIdx.x;  // 512 threads, one per code

    float cj = ((ws[PCNT_OFF + 0*K + j] + ws[PCNT_OFF + 1*K + j])
              + (ws[PCNT_OFF + 2*K + j] + ws[PCNT_OFF + 3*K + j]));
    float ncs = DECAYF * cluster_size[j] + OMDF * cj;
    out[NCS_OFF + j] = ncs;

    // diff: sum 2048 block partials (deterministic, R0 grouping)
    float dsum = 0.0f;
    #pragma unroll
    for (int k = 0; k < NBLK_ASSIGN / 512; ++k)
        dsum += ws[DPART_OFF + k * 512 + j];

    float s = ncs;
    #pragma unroll
    for (int off = 32; off > 0; off >>= 1) {
        s    += __shfl_down(s, off);
        dsum += __shfl_down(dsum, off);
    }
    if ((j & 63) == 0) { wsum[j >> 6] = s; dsum_sh[j >> 6] = dsum; }
    __syncthreads();
    if (j == 0) {
        float n = 0.f, dtot = 0.f;
        #pragma unroll
        for (int w = 0; w < 8; ++w) { n += wsum[w]; dtot += dsum_sh[w]; }
        ws[NSH_OFF] = n;
        out[DIFF_OFF] = dtot * (1.0f / 8388608.0f);  // 2^23: exact
    }
}

// ============ finalize stage 2: embed EMA + normalize — 64 blocks ========
__global__ __launch_bounds__(512) void vq_finalize2(
    const float* __restrict__ embed_avg,
    const float* __restrict__ ws,
    float* __restrict__ out)
{
    int d = blockIdx.x;     // 0..63
    int j = threadIdx.x;    // 0..511

    float ncs = out[NCS_OFF + j];
    float n   = ws[NSH_OFF];
    float csz = (ncs + EPSF) / (n + (float)K * EPSF) * n;

    float es = ((ws[PESUM_OFF + ((size_t)0*K + j) * DIM + d]
               + ws[PESUM_OFF + ((size_t)1*K + j) * DIM + d])
              + (ws[PESUM_OFF + ((size_t)2*K + j) * DIM + d]
               + ws[PESUM_OFF + ((size_t)3*K + j) * DIM + d]));
    float ea = DECAYF * embed_avg[d * K + j] + OMDF * es;
    out[NEA_OFF + d * K + j] = ea;        // coalesced over j
    out[NE_OFF  + d * K + j] = ea / csz;
}

// ============ launch ============
extern "C" void kernel_launch(void* const* d_in, const int* in_sizes, int n_in,
                              void* d_out, int out_size, void* d_ws, size_t ws_size,
                              hipStream_t stream) {
    const float* x            = (const float*)d_in[0];
    const float* embed        = (const float*)d_in[1];
    const float* cluster_size = (const float*)d_in[2];
    const float* embed_avg    = (const float*)d_in[3];
    float* out = (float*)d_out;
    float* ws  = (float*)d_ws;
    int*   indI = (int*)(ws + INDI_OFF);

    vq_prep<<<K / 256, 256, 0, stream>>>(embed, ws);
    vq_assign<<<NBLK_ASSIGN, 256, 0, stream>>>(
        x, ws + ET_OFF, ws + C_OFF, indI, ws + DPART_OFF, out);
    vq_stats<<<K * 4, 512, 0, stream>>>(
        x, indI, ws + PCNT_OFF, ws + PESUM_OFF);
    vq_finalize1<<<1, K, 0, stream>>>(cluster_size, ws, out);
    vq_finalize2<<<DIM, K, 0, stream>>>(embed_avg, ws, out);
}

// Round 11
// 268.764 us; speedup vs baseline: 3.8585x; 3.8585x over previous
//
#include <hip/hip_runtime.h>

// ---------------- problem constants ----------------
#define NVEC  131072      // 32*4096 vectors
#define DIM   64
#define K     512
#define DECAYF 0.99f
#define OMDF   0.01f
#define EPSF   1e-5f
#define VPB   128                 // vectors per block: 64 lanes x 2 vectors
#define NBLK_ASSIGN (NVEC / VPB)  // 1024 blocks, 4 waves each

// ---------------- output layout (floats, concatenated in return order) ----
#define Q_OFF    0
#define DIFF_OFF 8388608
#define IND_OFF  8388609
#define NE_OFF   8519681
#define NCS_OFF  8552449
#define NEA_OFF  8552961

// ---------------- ws layout (floats) — ~1.2 MB ----
#define ET_OFF    0        // E^T : K x DIM
#define C_OFF     32768    // np-order sum(E*E, axis=0) : K
#define DPART_OFF 33280    // per-assign-block diff partials : 1024
#define INDI_OFF  35328    // int copy of indices : NVEC
#define PCNT_OFF  166400   // count partials : 4 x K
#define PESUM_OFF 168448   // esum partials : 4 x K x DIM
#define NSH_OFF   299520   // (unused after finalize merge; kept for layout)
// end: 299521 floats = 1.17 MB (known-safe: r4 used 1.33 MB)

// ============ prep: transpose embed -> E^T, C_j = np.sum(E*E, axis=0) ====
__global__ __launch_bounds__(256) void vq_prep(const float* __restrict__ embed,
                                               float* __restrict__ ws) {
    #pragma clang fp contract(off)
    int j = blockIdx.x * 256 + threadIdx.x;
    float c = 0.0f;
    for (int d = 0; d < DIM; ++d) {
        float v = embed[d * K + j];           // coalesced across j
        ws[ET_OFF + j * DIM + d] = v;
        float t = v * v;
        c = c + t;
    }
    ws[C_OFF + j] = c;
}

// ============ main: np-fp32-replica argmin — R9-exact (best: 163 µs) =====
// Verdict after 10 rounds: SMEM e-stream + R=2 dual-chain + wpe(3) is the
// measured optimum. VMEM e-delivery is a DEAD END (R2: 592 µs latency
// death; R10: 973 µs — explicit dbuf spilled, WRITE 124 MB). LDS broadcast
// oversubscribes the DS pipe 3x (R3: 254 µs). R9's residual: ~70 µs VALU
// busy (the floor) + SMEM-latency stall at ~2.3 w/SIMD, with ~30 MB
// one-time spill that resisted unroll (R9) and epilogue (R8) fixes.
__global__ __launch_bounds__(256)
__attribute__((amdgpu_waves_per_eu(3)))
void vq_assign(
    const float* __restrict__ x,
    const float* __restrict__ ET,      // ws + ET_OFF
    const float* __restrict__ C,       // ws + C_OFF
    int*   __restrict__ indI,          // ws + INDI_OFF
    float* __restrict__ dpart,         // ws + DPART_OFF
    float* __restrict__ out)
{
    #pragma clang fp contract(off)
    __shared__ float sda[4][64], sdb[4][64];
    __shared__ int   sia[4][64], sib[4][64];
    __shared__ int   sba[64], sbb[64];
    __shared__ float wdl[4];

    int lane = threadIdx.x & 63;
    int wq   = __builtin_amdgcn_readfirstlane(threadIdx.x >> 6); // 0..3
    int va   = blockIdx.x * VPB + lane;
    int vb   = va + 64;
    const float* fxa = x + (size_t)va * DIM;
    const float* fxb = x + (size_t)vb * DIM;

    float fa[DIM], fb[DIM];
    #pragma unroll
    for (int k = 0; k < DIM / 4; ++k) {
        float4 t = ((const float4*)fxa)[k];
        fa[4*k+0] = t.x; fa[4*k+1] = t.y; fa[4*k+2] = t.z; fa[4*k+3] = t.w;
    }
    #pragma unroll
    for (int k = 0; k < DIM / 4; ++k) {
        float4 t = ((const float4*)fxb)[k];
        fb[4*k+0] = t.x; fb[4*k+1] = t.y; fb[4*k+2] = t.z; fb[4*k+3] = t.w;
    }

    // Pin fa/fb in VGPRs (identity asm: values defined by asm can't be
    // rematerialized from memory).
    #define PIN16(a, b) asm volatile("" \
        : "+v"(a[(b)+0]),  "+v"(a[(b)+1]),  "+v"(a[(b)+2]),  "+v"(a[(b)+3]), \
          "+v"(a[(b)+4]),  "+v"(a[(b)+5]),  "+v"(a[(b)+6]),  "+v"(a[(b)+7]), \
          "+v"(a[(b)+8]),  "+v"(a[(b)+9]),  "+v"(a[(b)+10]), "+v"(a[(b)+11]), \
          "+v"(a[(b)+12]), "+v"(a[(b)+13]), "+v"(a[(b)+14]), "+v"(a[(b)+15]))
    PIN16(fa, 0); PIN16(fa, 16); PIN16(fa, 32); PIN16(fa, 48);
    PIN16(fb, 0); PIN16(fb, 16); PIN16(fb, 32); PIN16(fb, 48);
    #undef PIN16

    // A per vector: numpy pairwise, n=64 -> 8 accumulators stride 8, then
    // ((r0+r1)+(r2+r3))+((r4+r5)+(r6+r7)). Plain mul+add (contract off).
    float ra[8], rb[8];
    #pragma unroll
    for (int k = 0; k < 8; ++k) { ra[k] = fa[k] * fa[k]; rb[k] = fb[k] * fb[k]; }
    #pragma unroll
    for (int b = 1; b < 8; ++b) {
        #pragma unroll
        for (int k = 0; k < 8; ++k) {
            float t0 = fa[8*b + k] * fa[8*b + k];
            ra[k] = ra[k] + t0;
            float t1 = fb[8*b + k] * fb[8*b + k];
            rb[k] = rb[k] + t1;
        }
    }
    float Aa = ((ra[0] + ra[1]) + (ra[2] + ra[3])) + ((ra[4] + ra[5]) + (ra[6] + ra[7]));
    float Ab = ((rb[0] + rb[1]) + (rb[2] + rb[3])) + ((rb[4] + rb[5]) + (rb[6] + rb[7]));

    // wave-uniform code segment -> s_load e-stream; one scalar feeds 2 FMAs.
    const float* eseg = ET + (size_t)wq * 128 * DIM;
    const float* Cseg = C + wq * 128;
    float bda = 3.0e38f, bdb = 3.0e38f;
    int   bia = wq * 128, bib = wq * 128;
    #pragma unroll 1
    for (int jj = 0; jj < 128; ++jj) {
        const float* e = eseg + jj * DIM;
        float ma = 0.0f, mb = 0.0f;
        #pragma unroll
        for (int d = 0; d < DIM; ++d) {
            float ev = e[d];
            ma = __builtin_fmaf(fa[d], ev, ma);
            mb = __builtin_fmaf(fb[d], ev, mb);
        }
        int j = wq * 128 + jj;
        float Cv = Cseg[jj];
        float t1a = 2.0f * ma;           // exact (x2)
        float t2a = Aa - t1a;            // rounded
        float da  = t2a + Cv;            // rounded
        float t1b = 2.0f * mb;
        float t2b = Ab - t1b;
        float db  = t2b + Cv;
        if (da < bda) { bda = da; bia = j; }
        if (db < bdb) { bdb = db; bib = j; }
    }

    sda[wq][lane] = bda; sia[wq][lane] = bia;
    sdb[wq][lane] = bdb; sib[wq][lane] = bib;
    __syncthreads();

    if (wq == 0) {
        // 4-way merge, ascending q, tie -> smaller index: numpy first-min.
        float bd = sda[0][lane]; int bi = sia[0][lane];
        #pragma unroll
        for (int q = 1; q < 4; ++q) {
            float d2 = sda[q][lane]; int i2 = sia[q][lane];
            if (d2 < bd || (d2 == bd && i2 < bi)) { bd = d2; bi = i2; }
        }
        sba[lane] = bi;
        out[IND_OFF + va] = (float)bi;   // coalesced
        indI[va] = bi;

        bd = sdb[0][lane]; bi = sib[0][lane];
        #pragma unroll
        for (int q = 1; q < 4; ++q) {
            float d2 = sdb[q][lane]; int i2 = sib[q][lane];
            if (d2 < bd || (d2 == bd && i2 < bi)) { bd = d2; bi = i2; }
        }
        sbb[lane] = bi;
        out[IND_OFF + vb] = (float)bi;
        indI[vb] = bi;
    }
    __syncthreads();

    // epilogue: wave0 -> va rows (vs pinned fa), wave1 -> vb rows (vs fb);
    // waves 2,3 idle (wdl = 0, dpart grouping stays wdl[0]+wdl[1]).
    float dl = 0.0f;
    if (wq == 0) {
        int bsel = sba[lane];
        const float4* qr = (const float4*)(ET + (size_t)bsel * DIM);
        float4* orow = (float4*)(out + Q_OFF + (size_t)va * DIM);
        #pragma unroll
        for (int k = 0; k < 16; ++k) {
            float4 tq = qr[k];
            float r0 = tq.x - fa[4*k+0];
            float r1 = tq.y - fa[4*k+1];
            float r2 = tq.z - fa[4*k+2];
            float r3 = tq.w - fa[4*k+3];
            dl = __builtin_fmaf(r0, r0, dl); dl = __builtin_fmaf(r1, r1, dl);
            dl = __builtin_fmaf(r2, r2, dl); dl = __builtin_fmaf(r3, r3, dl);
            orow[k] = tq;
        }
    } else if (wq == 1) {
        int bsel = sbb[lane];
        const float4* qr = (const float4*)(ET + (size_t)bsel * DIM);
        float4* orow = (float4*)(out + Q_OFF + (size_t)vb * DIM);
        #pragma unroll
        for (int k = 0; k < 16; ++k) {
            float4 tq = qr[k];
            float r0 = tq.x - fb[4*k+0];
            float r1 = tq.y - fb[4*k+1];
            float r2 = tq.z - fb[4*k+2];
            float r3 = tq.w - fb[4*k+3];
            dl = __builtin_fmaf(r0, r0, dl); dl = __builtin_fmaf(r1, r1, dl);
            dl = __builtin_fmaf(r2, r2, dl); dl = __builtin_fmaf(r3, r3, dl);
            orow[k] = tq;
        }
    }

    #pragma unroll
    for (int off = 32; off > 0; off >>= 1) dl += __shfl_down(dl, off);
    if (lane == 0) wdl[wq] = dl;
    __syncthreads();
    if (threadIdx.x == 0)
        dpart[blockIdx.x] = ((wdl[0] + wdl[1]) + (wdl[2] + wdl[3]));
}

// ============ stats: 4-code grouping, int4 ballot scan ====================
// Block (jg = bid>>2, q = bid&3) handles codes j0..j0+3 (j0 = jg*4): wave w
// scans segment q*8+w (4096 ids) ONCE and ballots against 4 codes — id-load
// traffic drops 4x (256->64 MB) vs one-code-per-block. Per-(j,seg)
// accumulation order (ascending i, component, bit) and both reduce trees
// are unchanged -> partials bit-identical to the proven kernel.
__global__ __launch_bounds__(512) void vq_stats(
    const float* __restrict__ x,
    const int* __restrict__ indI,      // ws + INDI_OFF
    float* __restrict__ pcnt,          // ws + PCNT_OFF   [4][K]
    float* __restrict__ pesum)         // ws + PESUM_OFF  [4][K][DIM]
{
    __shared__ float p[4][8][DIM];     // [jj][wave][dim] = 8 KB
    __shared__ float c[4][8];
    int jg   = blockIdx.x >> 2;        // 0..127
    int q    = blockIdx.x & 3;
    int lane = threadIdx.x & 63;
    int w    = __builtin_amdgcn_readfirstlane(threadIdx.x >> 6);
    int j0   = jg * 4;

    int seg  = q * 8 + w;              // 0..31
    int base = seg * (NVEC / 32);      // 4096 ids per segment

    float acc[4] = {0.0f, 0.0f, 0.0f, 0.0f};
    int   cnt[4] = {0, 0, 0, 0};
    for (int i = 0; i < NVEC / 32; i += 256) {
        int4 idv = ((const int4*)(indI + base + i))[lane];  // 256 ids/wave
        #pragma unroll
        for (int jj = 0; jj < 4; ++jj) {
            int j = j0 + jj;
            unsigned long long m0 = __ballot(idv.x == j);
            unsigned long long m1 = __ballot(idv.y == j);
            unsigned long long m2 = __ballot(idv.z == j);
            unsigned long long m3 = __ballot(idv.w == j);
            cnt[jj] += (int)(__popcll(m0) + __popcll(m1)
                           + __popcll(m2) + __popcll(m3));
            while (m0) { int b = __builtin_ctzll(m0); m0 &= m0 - 1;
                         acc[jj] += x[(size_t)(base + i + 4*b + 0) * DIM + lane]; }
            while (m1) { int b = __builtin_ctzll(m1); m1 &= m1 - 1;
                         acc[jj] += x[(size_t)(base + i + 4*b + 1) * DIM + lane]; }
            while (m2) { int b = __builtin_ctzll(m2); m2 &= m2 - 1;
                         acc[jj] += x[(size_t)(base + i + 4*b + 2) * DIM + lane]; }
            while (m3) { int b = __builtin_ctzll(m3); m3 &= m3 - 1;
                         acc[jj] += x[(size_t)(base + i + 4*b + 3) * DIM + lane]; }
        }
    }
    #pragma unroll
    for (int jj = 0; jj < 4; ++jj) {
        p[jj][w][lane] = acc[jj];
        if (lane == 0) c[jj][w] = (float)cnt[jj];
    }
    __syncthreads();
    if (w == 0) {
        #pragma unroll
        for (int jj = 0; jj < 4; ++jj) {
            float s = ((p[jj][0][lane] + p[jj][1][lane])
                     + (p[jj][2][lane] + p[jj][3][lane]))
                    + ((p[jj][4][lane] + p[jj][5][lane])
                     + (p[jj][6][lane] + p[jj][7][lane]));
            pesum[((size_t)q * K + (j0 + jj)) * DIM + lane] = s;
            if (lane == 0)
                pcnt[q * K + (j0 + jj)] =
                    ((c[jj][0] + c[jj][1]) + (c[jj][2] + c[jj][3]))
                  + ((c[jj][4] + c[jj][5]) + (c[jj][6] + c[jj][7]));
        }
    }
}

// ============ finalize (merged): 64 blocks, one per d ====================
// Each block recomputes ncs[j] and n with the EXACT op sequence of the old
// finalize1 (same loads, same shuffle tree, same ascending 8-sum) -> n is
// bit-identical in every block; no inter-kernel dependency. Block 0
// additionally writes ncs, diff. Saves one launch + the serial fin1 pass.
__global__ __launch_bounds__(512) void vq_finalize(
    const float* __restrict__ cluster_size,
    const float* __restrict__ embed_avg,
    const float* __restrict__ ws,
    float* __restrict__ out)
{
    __shared__ float wsum[8];
    __shared__ float dsum_sh[8];
    __shared__ float n_sh;
    int d = blockIdx.x;     // 0..63
    int j = threadIdx.x;    // 0..511

    float cj = ((ws[PCNT_OFF + 0*K + j] + ws[PCNT_OFF + 1*K + j])
              + (ws[PCNT_OFF + 2*K + j] + ws[PCNT_OFF + 3*K + j]));
    float ncs = DECAYF * cluster_size[j] + OMDF * cj;
    if (d == 0) out[NCS_OFF + j] = ncs;

    // diff partial sum only needed in block 0 (d uniform per block)
    float dsum = 0.0f;
    if (d == 0) {
        #pragma unroll
        for (int k = 0; k < NBLK_ASSIGN / 512; ++k)
            dsum += ws[DPART_OFF + k * 512 + j];
    }

    float s = ncs;
    #pragma unroll
    for (int off = 32; off > 0; off >>= 1) {
        s    += __shfl_down(s, off);
        dsum += __shfl_down(dsum, off);
    }
    if ((j & 63) == 0) { wsum[j >> 6] = s; dsum_sh[j >> 6] = dsum; }
    __syncthreads();
    if (j == 0) {
        float n = 0.f, dtot = 0.f;
        #pragma unroll
        for (int w = 0; w < 8; ++w) { n += wsum[w]; dtot += dsum_sh[w]; }
        n_sh = n;
        if (d == 0) out[DIFF_OFF] = dtot * (1.0f / 8388608.0f);  // 2^23: exact
    }
    __syncthreads();
    float n   = n_sh;
    float csz = (ncs + EPSF) / (n + (float)K * EPSF) * n;

    float es = ((ws[PESUM_OFF + ((size_t)0*K + j) * DIM + d]
               + ws[PESUM_OFF + ((size_t)1*K + j) * DIM + d])
              + (ws[PESUM_OFF + ((size_t)2*K + j) * DIM + d]
               + ws[PESUM_OFF + ((size_t)3*K + j) * DIM + d]));
    float ea = DECAYF * embed_avg[d * K + j] + OMDF * es;
    out[NEA_OFF + d * K + j] = ea;        // coalesced over j
    out[NE_OFF  + d * K + j] = ea / csz;
}

// ============ launch ============
extern "C" void kernel_launch(void* const* d_in, const int* in_sizes, int n_in,
                              void* d_out, int out_size, void* d_ws, size_t ws_size,
                              hipStream_t stream) {
    const float* x            = (const float*)d_in[0];
    const float* embed        = (const float*)d_in[1];
    const float* cluster_size = (const float*)d_in[2];
    const float* embed_avg    = (const float*)d_in[3];
    float* out = (float*)d_out;
    float* ws  = (float*)d_ws;
    int*   indI = (int*)(ws + INDI_OFF);

    vq_prep<<<K / 256, 256, 0, stream>>>(embed, ws);
    vq_assign<<<NBLK_ASSIGN, 256, 0, stream>>>(
        x, ws + ET_OFF, ws + C_OFF, indI, ws + DPART_OFF, out);
    vq_stats<<<(K / 4) * 4, 512, 0, stream>>>(
        x, indI, ws + PCNT_OFF, ws + PESUM_OFF);
    vq_finalize<<<DIM, K, 0, stream>>>(cluster_size, embed_avg, ws, out);
}